// Round 10
// baseline (230.289 us; speedup 1.0000x reference)
//
#include <hip/hip_runtime.h>
#include <hip/hip_bf16.h>

// CapsuleLayer dynamic routing. B=64, I=2048, D=16, J=32, K=16, routings=3.
// Proven: f32 in/out, ws >= 142.74 MB (uhat 128Mi + spart 8Mi + vsum; do NOT
// grow spart). Round-8 lesson: never pass min-waves to __launch_bounds__.
// Round 10:
//  - produce: ctile shrunk to 8-j groups (LDS 59->42 KB, 2->3 blocks/CU);
//    x-load hoisted above __syncthreads.
//  - route1: 4-deep rotating prefetch (8 rows in flight), rcp instead of div.
//  - sum0/squash: unchanged.

#define B_ 64
#define I_ 2048
#define D_ 16
#define J_ 32
#define K_ 16
#define JK 512  // J_*K_

typedef __attribute__((ext_vector_type(8))) short short8;
typedef __attribute__((ext_vector_type(4))) float float4v;

__device__ __forceinline__ unsigned short f2bf(float f) {
    union { float f; unsigned int i; } v;
    v.f = f;
    const unsigned int x = v.i;
    return (unsigned short)((x + 0x7fffu + ((x >> 16) & 1u)) >> 16);  // RNE
}

__device__ __forceinline__ void unpack8(const uint4 r, float* u) {
    union { unsigned int i; float f; } t;
    t.i = r.x << 16;         u[0] = t.f;
    t.i = r.x & 0xffff0000u; u[1] = t.f;
    t.i = r.y << 16;         u[2] = t.f;
    t.i = r.y & 0xffff0000u; u[3] = t.f;
    t.i = r.z << 16;         u[4] = t.f;
    t.i = r.z & 0xffff0000u; u[5] = t.f;
    t.i = r.w << 16;         u[6] = t.f;
    t.i = r.w & 0xffff0000u; u[7] = t.f;
}

// ---------------------------------------------------------------------------
// Producer (MFMA): grid I_ x 256 (4 waves = 4 b-tiles of 16).
// LDS: wlds 24 KB (W_i bf16 [j][cap_k][d]) + ctile 17.4 KB (per-wave 16 x 136
// bf16 transpose tile, 8 j per group) + zbuf. Total ~42 KB -> 3 blocks/CU.
// ---------------------------------------------------------------------------
__global__ __launch_bounds__(256)
void caps_produce(const float* __restrict__ x, const float* __restrict__ W,
                  unsigned short* __restrict__ uhat) {
    __shared__ unsigned short wlds[32 * 384];      // 24 KB
    __shared__ unsigned short zbuf[8];             // 16 B zeros
    __shared__ unsigned short ctile[4][16 * 136];  // 17.4 KB
    const int i = blockIdx.x;
    const int tid = threadIdx.x;

    if (tid < 8) zbuf[tid] = 0;

    const int lane = tid & 63;
    const int wv = tid >> 6;
    const int quad = lane >> 4;
    const int l15 = lane & 15;
    const int b = wv * 16 + l15;

    // x-load first: independent of LDS staging, overlaps it.
    union { uint4 u; short8 s; } bfrag;
    {
        const float* xp = x + ((size_t)b * I_ + i) * D_ + (quad & 1) * 8;
        const float4 x0 = reinterpret_cast<const float4*>(xp)[0];
        const float4 x1 = reinterpret_cast<const float4*>(xp)[1];
        bfrag.u.x = ((unsigned int)f2bf(x0.y) << 16) | f2bf(x0.x);
        bfrag.u.y = ((unsigned int)f2bf(x0.w) << 16) | f2bf(x0.z);
        bfrag.u.z = ((unsigned int)f2bf(x1.y) << 16) | f2bf(x1.x);
        bfrag.u.w = ((unsigned int)f2bf(x1.w) << 16) | f2bf(x1.z);
        if (quad >= 2) { bfrag.u.x = 0; bfrag.u.y = 0; bfrag.u.z = 0; bfrag.u.w = 0; }
    }

    // stage W_i (32 KB f32) -> LDS bf16 [j][cap_k][d]
    {
        const float* wbase = W + (size_t)i * (J_ * D_ * K_);
        const int k = tid & 15;
#pragma unroll
        for (int half = 0; half < 2; ++half) {
            const int j = (tid >> 4) + half * 16;
            const float* p = wbase + j * (D_ * K_) + k;
            float vals[16];
#pragma unroll
            for (int d = 0; d < 16; ++d) vals[d] = p[d * K_];
            unsigned int pk[8];
#pragma unroll
            for (int q = 0; q < 8; ++q)
                pk[q] = ((unsigned int)f2bf(vals[2 * q + 1]) << 16) |
                        f2bf(vals[2 * q]);
            uint4* dst = reinterpret_cast<uint4*>(wlds + j * 384 + k * 24);
            uint4 w0; w0.x = pk[0]; w0.y = pk[1]; w0.z = pk[2]; w0.w = pk[3];
            uint4 w1; w1.x = pk[4]; w1.y = pk[5]; w1.z = pk[6]; w1.w = pk[7];
            dst[0] = w0; dst[1] = w1;
        }
    }
    __syncthreads();

    const unsigned short* aptr =
        (quad >= 2) ? zbuf : (wlds + l15 * 24 + (quad & 1) * 8);
    const int astride = (quad >= 2) ? 0 : 384;
    unsigned short* ct = &ctile[wv][0];

    for (int jg = 0; jg < 4; ++jg) {
#pragma unroll
        for (int jj = 0; jj < 8; ++jj) {
            const int j = jg * 8 + jj;
            union { uint4 u; short8 s; } af;
            af.u = *reinterpret_cast<const uint4*>(aptr + (size_t)j * astride);
            float4v acc = {0.f, 0.f, 0.f, 0.f};
            acc = __builtin_amdgcn_mfma_f32_16x16x32_bf16(af.s, bfrag.s, acc,
                                                          0, 0, 0);
            uint2 pk;
            pk.x = ((unsigned int)f2bf(acc[1]) << 16) | f2bf(acc[0]);
            pk.y = ((unsigned int)f2bf(acc[3]) << 16) | f2bf(acc[2]);
            // [b=l15][jj*16 + quad*4 .. +3] in the wave's 16x136 tile
            *reinterpret_cast<uint2*>(ct + l15 * 136 + jj * 16 + quad * 4) = pk;
        }
        // same-wave readback (lgkmcnt ordering): 4 instrs x (4 rows x 256 B)
#pragma unroll
        for (int r = 0; r < 4; ++r) {
            const int bsub = r * 4 + (lane >> 4);
            const int c16 = lane & 15;
            const uint4 val = *reinterpret_cast<const uint4*>(
                ct + bsub * 136 + c16 * 8);
            *reinterpret_cast<uint4*>(
                uhat + ((size_t)(wv * 16 + bsub) * I_ + i) * JK + jg * 128 +
                c16 * 8) = val;
        }
    }
}

// ---------------------------------------------------------------------------
// Round-0 column sum (uniform coupling): grid = 64 b x 4 q, 256 threads.
// ---------------------------------------------------------------------------
__global__ __launch_bounds__(256)
void caps_sum0(const unsigned short* __restrict__ uhat,
               float* __restrict__ spart2) {
    __shared__ float part[4][512];
    const int bq = blockIdx.x;
    const int b = bq >> 2, q = bq & 3;
    const int lane = threadIdx.x & 63;
    const int w = threadIdx.x >> 6;

    const unsigned short* up =
        uhat + ((size_t)b * I_ + q * 512 + w * 128) * JK + lane * 8;

    float acc[8];
#pragma unroll
    for (int k = 0; k < 8; ++k) acc[k] = 0.f;

    for (int ii = 0; ii < 128; ii += 4) {
        uint4 r[4];
#pragma unroll
        for (int s = 0; s < 4; ++s)
            r[s] = *reinterpret_cast<const uint4*>(up + (size_t)(ii + s) * JK);
#pragma unroll
        for (int s = 0; s < 4; ++s) {
            float u[8];
            unpack8(r[s], u);
#pragma unroll
            for (int k = 0; k < 8; ++k) acc[k] += u[k];
        }
    }

    float4 o0, o1;
    o0.x = acc[0]; o0.y = acc[1]; o0.z = acc[2]; o0.w = acc[3];
    o1.x = acc[4]; o1.y = acc[5]; o1.z = acc[6]; o1.w = acc[7];
    reinterpret_cast<float4*>(&part[w][lane * 8])[0] = o0;
    reinterpret_cast<float4*>(&part[w][lane * 8])[1] = o1;
    __syncthreads();

    const int t = threadIdx.x;
#pragma unroll
    for (int e = 0; e < 2; ++e) {
        const int jk = t * 2 + e;
        spart2[(size_t)bq * 512 + jk] =
            part[0][jk] + part[1][jk] + part[2][jk] + part[3][jk];
    }
}

__global__ __launch_bounds__(512)
void caps_squash0(const float* __restrict__ spart2, float* __restrict__ vsum) {
    const int bl = blockIdx.x;
    const int jk = threadIdx.x;
    float s = spart2[(size_t)(bl * 4 + 0) * 512 + jk] +
              spart2[(size_t)(bl * 4 + 1) * 512 + jk] +
              spart2[(size_t)(bl * 4 + 2) * 512 + jk] +
              spart2[(size_t)(bl * 4 + 3) * 512 + jk];
    s *= (1.f / 32.f);
    float q = s * s;
    q += __shfl_xor(q, 1, 64);
    q += __shfl_xor(q, 2, 64);
    q += __shfl_xor(q, 4, 64);
    q += __shfl_xor(q, 8, 64);
    const float scale = q / ((1.f + q) * sqrtf(q + 1e-7f));
    vsum[bl * JK + jk] = scale * s;
}

// ---------------------------------------------------------------------------
// Softmax routing pass: 4096 one-wave blocks = 64 b x 64 chunks (32 i).
// lane: h = lane>>5 (i parity), j = lane&31 -> u_hat[b,i,j,0:16] (32B/lane).
// 4-deep rotating prefetch (8 i-rows in flight). Softmax denom = 5 shfl in
// the 32-half; c = e*rcp(S). Natural VGPR (~100), no min-waves forcing.
// ---------------------------------------------------------------------------
__global__ __launch_bounds__(64)
void caps_route1(const unsigned short* __restrict__ uhat,
                 const float* __restrict__ vsum, float* __restrict__ spart) {
    const int lane = threadIdx.x;
    const int bl = blockIdx.x >> 6;
    const int chunk = blockIdx.x & 63;
    const int h = lane >> 5;
    const int j = lane & 31;

    float v[16];
    {
        const float4* vp =
            reinterpret_cast<const float4*>(vsum + bl * JK + j * 16);
        const float4 a0 = vp[0], a1 = vp[1], a2 = vp[2], a3 = vp[3];
        v[0] = a0.x; v[1] = a0.y; v[2] = a0.z; v[3] = a0.w;
        v[4] = a1.x; v[5] = a1.y; v[6] = a1.z; v[7] = a1.w;
        v[8] = a2.x; v[9] = a2.y; v[10] = a2.z; v[11] = a2.w;
        v[12] = a3.x; v[13] = a3.y; v[14] = a3.z; v[15] = a3.w;
    }

    float acc[16];
#pragma unroll
    for (int k = 0; k < 16; ++k) acc[k] = 0.f;

    const unsigned short* up =
        uhat + ((size_t)bl * I_ + chunk * 32 + h) * JK + j * 16;

    uint4 pf[4][2];
#pragma unroll
    for (int s = 0; s < 4; ++s) {
        const uint4* p = reinterpret_cast<const uint4*>(up + (size_t)s * 2 * JK);
        pf[s][0] = p[0];
        pf[s][1] = p[1];
    }

#pragma unroll
    for (int t = 0; t < 16; ++t) {
        const int slot = t & 3;
        float u[16];
        unpack8(pf[slot][0], u);
        unpack8(pf[slot][1], u + 8);
        if (t + 4 < 16) {
            const uint4* p =
                reinterpret_cast<const uint4*>(up + (size_t)(t + 4) * 2 * JK);
            pf[slot][0] = p[0];
            pf[slot][1] = p[1];
        }
        float p = 0.f;
#pragma unroll
        for (int k = 0; k < 16; ++k) p += u[k] * v[k];
        const float e = __expf(p);  // |p| bounded; f32-safe
        float S = e;                // denom over the 32 j's of this half
        S += __shfl_xor(S, 1, 64);
        S += __shfl_xor(S, 2, 64);
        S += __shfl_xor(S, 4, 64);
        S += __shfl_xor(S, 8, 64);
        S += __shfl_xor(S, 16, 64);
        const float c = e * __builtin_amdgcn_rcpf(S);
#pragma unroll
        for (int k = 0; k < 16; ++k) acc[k] += c * u[k];
    }

    // merge the two i-parity halves (same (b,j,k))
#pragma unroll
    for (int k = 0; k < 16; ++k) acc[k] += __shfl_xor(acc[k], 32, 64);

    if (h == 0) {
        float* sp = spart + ((size_t)chunk * B_ + bl) * JK + j * 16;
#pragma unroll
        for (int q = 0; q < 4; ++q) {
            float4 o;
            o.x = acc[q * 4 + 0]; o.y = acc[q * 4 + 1];
            o.z = acc[q * 4 + 2]; o.w = acc[q * 4 + 3];
            reinterpret_cast<float4*>(sp)[q] = o;
        }
    }
}

// ---------------------------------------------------------------------------
// Squash for rounds 1,2: reduce spart[64][B][512].
// MODE 1: vsum += v.  MODE 2: out = v.
// ---------------------------------------------------------------------------
template <int MODE>
__global__ __launch_bounds__(512)
void caps_squash(const float* __restrict__ spart, float* __restrict__ vsum,
                 float* __restrict__ out) {
    const int bl = blockIdx.x;
    const int jk = threadIdx.x;
    float s = 0.f;
#pragma unroll 8
    for (int p = 0; p < 64; ++p)
        s += spart[((size_t)p * B_ + bl) * JK + jk];
    float q = s * s;
    q += __shfl_xor(q, 1, 64);
    q += __shfl_xor(q, 2, 64);
    q += __shfl_xor(q, 4, 64);
    q += __shfl_xor(q, 8, 64);
    const float scale = q / ((1.f + q) * sqrtf(q + 1e-7f));
    const float v = scale * s;
    if (MODE == 1) vsum[bl * JK + jk] += v;
    else           out[(size_t)bl * JK + jk] = v;
}

// ---------------------------------------------------------------------------
extern "C" void kernel_launch(void* const* d_in, const int* in_sizes, int n_in,
                              void* d_out, int out_size, void* d_ws,
                              size_t ws_size, hipStream_t stream) {
    const float* x = (const float*)d_in[0];  // [B,I,D] f32
    const float* W = (const float*)d_in[1];  // [I,J,D,K] f32
    float* out = (float*)d_out;              // [B,J,K] f32

    char* ws = (char*)d_ws;
    unsigned short* uhat = (unsigned short*)ws;                // 128 MiB
    float* spart = (float*)(ws + (size_t)B_ * I_ * JK * 2);    // 8 MiB
    float* vsum = spart + (size_t)64 * B_ * JK;                // 128 KiB

    caps_produce<<<I_, 256, 0, stream>>>(x, W, uhat);

    caps_sum0<<<256, 256, 0, stream>>>(uhat, spart);
    caps_squash0<<<B_, 512, 0, stream>>>(spart, vsum);

    caps_route1<<<4096, 64, 0, stream>>>(uhat, vsum, spart);
    caps_squash<1><<<B_, 512, 0, stream>>>(spart, vsum, out);

    caps_route1<<<4096, 64, 0, stream>>>(uhat, vsum, spart);
    caps_squash<2><<<B_, 512, 0, stream>>>(spart, vsum, out);
}

// Round 11
// 195.244 us; speedup vs baseline: 1.1795x; 1.1795x over previous
//
#include <hip/hip_runtime.h>
#include <hip/hip_bf16.h>

// CapsuleLayer dynamic routing. B=64, I=2048, D=16, J=32, K=16, routings=3.
// Proven: f32 in/out, ws >= 142.74 MB. Lessons: never force min-waves
// (round-8 spill); deeper VMEM prefetch does NOT help route1 (rounds 7,10).
// Round 11:
//  - route1: round-9 body, but softmax denominator via DPP row_shr/bcast15
//    adds (VALU pipe) + readlane, replacing 5 dependent ds_bpermute shuffles.
//  - sum0: grid 256 -> 1024 blocks (was 1 wave/SIMD, latency-bound).
//  - produce: round-10 version kept (best measured, ~46 us).

#define B_ 64
#define I_ 2048
#define D_ 16
#define J_ 32
#define K_ 16
#define JK 512  // J_*K_

typedef __attribute__((ext_vector_type(8))) short short8;
typedef __attribute__((ext_vector_type(4))) float float4v;

__device__ __forceinline__ unsigned short f2bf(float f) {
    union { float f; unsigned int i; } v;
    v.f = f;
    const unsigned int x = v.i;
    return (unsigned short)((x + 0x7fffu + ((x >> 16) & 1u)) >> 16);  // RNE
}

__device__ __forceinline__ void unpack8(const uint4 r, float* u) {
    union { unsigned int i; float f; } t;
    t.i = r.x << 16;         u[0] = t.f;
    t.i = r.x & 0xffff0000u; u[1] = t.f;
    t.i = r.y << 16;         u[2] = t.f;
    t.i = r.y & 0xffff0000u; u[3] = t.f;
    t.i = r.z << 16;         u[4] = t.f;
    t.i = r.z & 0xffff0000u; u[5] = t.f;
    t.i = r.w << 16;         u[6] = t.f;
    t.i = r.w & 0xffff0000u; u[7] = t.f;
}

// DPP-based add of a row-shifted copy: VALU pipe, no LDS.
template <int CTRL>
__device__ __forceinline__ float dpp_add(float x) {
    union { float f; int i; } a, b;
    a.f = x;
    b.i = __builtin_amdgcn_update_dpp(0, a.i, CTRL, 0xf, 0xf, false);
    return x + b.f;
}

// ---------------------------------------------------------------------------
// Producer (MFMA): round-10 version. grid I_ x 256 (4 waves = 4 b-tiles).
// ---------------------------------------------------------------------------
__global__ __launch_bounds__(256)
void caps_produce(const float* __restrict__ x, const float* __restrict__ W,
                  unsigned short* __restrict__ uhat) {
    __shared__ unsigned short wlds[32 * 384];      // 24 KB
    __shared__ unsigned short zbuf[8];             // 16 B zeros
    __shared__ unsigned short ctile[4][16 * 136];  // 17.4 KB
    const int i = blockIdx.x;
    const int tid = threadIdx.x;

    if (tid < 8) zbuf[tid] = 0;

    const int lane = tid & 63;
    const int wv = tid >> 6;
    const int quad = lane >> 4;
    const int l15 = lane & 15;
    const int b = wv * 16 + l15;

    union { uint4 u; short8 s; } bfrag;
    {
        const float* xp = x + ((size_t)b * I_ + i) * D_ + (quad & 1) * 8;
        const float4 x0 = reinterpret_cast<const float4*>(xp)[0];
        const float4 x1 = reinterpret_cast<const float4*>(xp)[1];
        bfrag.u.x = ((unsigned int)f2bf(x0.y) << 16) | f2bf(x0.x);
        bfrag.u.y = ((unsigned int)f2bf(x0.w) << 16) | f2bf(x0.z);
        bfrag.u.z = ((unsigned int)f2bf(x1.y) << 16) | f2bf(x1.x);
        bfrag.u.w = ((unsigned int)f2bf(x1.w) << 16) | f2bf(x1.z);
        if (quad >= 2) { bfrag.u.x = 0; bfrag.u.y = 0; bfrag.u.z = 0; bfrag.u.w = 0; }
    }

    {
        const float* wbase = W + (size_t)i * (J_ * D_ * K_);
        const int k = tid & 15;
#pragma unroll
        for (int half = 0; half < 2; ++half) {
            const int j = (tid >> 4) + half * 16;
            const float* p = wbase + j * (D_ * K_) + k;
            float vals[16];
#pragma unroll
            for (int d = 0; d < 16; ++d) vals[d] = p[d * K_];
            unsigned int pk[8];
#pragma unroll
            for (int q = 0; q < 8; ++q)
                pk[q] = ((unsigned int)f2bf(vals[2 * q + 1]) << 16) |
                        f2bf(vals[2 * q]);
            uint4* dst = reinterpret_cast<uint4*>(wlds + j * 384 + k * 24);
            uint4 w0; w0.x = pk[0]; w0.y = pk[1]; w0.z = pk[2]; w0.w = pk[3];
            uint4 w1; w1.x = pk[4]; w1.y = pk[5]; w1.z = pk[6]; w1.w = pk[7];
            dst[0] = w0; dst[1] = w1;
        }
    }
    __syncthreads();

    const unsigned short* aptr =
        (quad >= 2) ? zbuf : (wlds + l15 * 24 + (quad & 1) * 8);
    const int astride = (quad >= 2) ? 0 : 384;
    unsigned short* ct = &ctile[wv][0];

    for (int jg = 0; jg < 4; ++jg) {
#pragma unroll
        for (int jj = 0; jj < 8; ++jj) {
            const int j = jg * 8 + jj;
            union { uint4 u; short8 s; } af;
            af.u = *reinterpret_cast<const uint4*>(aptr + (size_t)j * astride);
            float4v acc = {0.f, 0.f, 0.f, 0.f};
            acc = __builtin_amdgcn_mfma_f32_16x16x32_bf16(af.s, bfrag.s, acc,
                                                          0, 0, 0);
            uint2 pk;
            pk.x = ((unsigned int)f2bf(acc[1]) << 16) | f2bf(acc[0]);
            pk.y = ((unsigned int)f2bf(acc[3]) << 16) | f2bf(acc[2]);
            *reinterpret_cast<uint2*>(ct + l15 * 136 + jj * 16 + quad * 4) = pk;
        }
#pragma unroll
        for (int r = 0; r < 4; ++r) {
            const int bsub = r * 4 + (lane >> 4);
            const int c16 = lane & 15;
            const uint4 val = *reinterpret_cast<const uint4*>(
                ct + bsub * 136 + c16 * 8);
            *reinterpret_cast<uint4*>(
                uhat + ((size_t)(wv * 16 + bsub) * I_ + i) * JK + jg * 128 +
                c16 * 8) = val;
        }
    }
}

// ---------------------------------------------------------------------------
// Round-0 column sum: grid = 64 b x 16 q (1024 blocks, 4/CU), 256 threads.
// Wave w sums i in [q*128 + w*32, +32); lane owns jk8 = lane*8 (16B dense).
// ---------------------------------------------------------------------------
__global__ __launch_bounds__(256)
void caps_sum0(const unsigned short* __restrict__ uhat,
               float* __restrict__ spart2) {
    __shared__ float part[4][512];
    const int bq = blockIdx.x;
    const int b = bq >> 4, q = bq & 15;
    const int lane = threadIdx.x & 63;
    const int w = threadIdx.x >> 6;

    const unsigned short* up =
        uhat + ((size_t)b * I_ + q * 128 + w * 32) * JK + lane * 8;

    float acc[8];
#pragma unroll
    for (int k = 0; k < 8; ++k) acc[k] = 0.f;

    for (int ii = 0; ii < 32; ii += 4) {
        uint4 r[4];
#pragma unroll
        for (int s = 0; s < 4; ++s)
            r[s] = *reinterpret_cast<const uint4*>(up + (size_t)(ii + s) * JK);
#pragma unroll
        for (int s = 0; s < 4; ++s) {
            float u[8];
            unpack8(r[s], u);
#pragma unroll
            for (int k = 0; k < 8; ++k) acc[k] += u[k];
        }
    }

    float4 o0, o1;
    o0.x = acc[0]; o0.y = acc[1]; o0.z = acc[2]; o0.w = acc[3];
    o1.x = acc[4]; o1.y = acc[5]; o1.z = acc[6]; o1.w = acc[7];
    reinterpret_cast<float4*>(&part[w][lane * 8])[0] = o0;
    reinterpret_cast<float4*>(&part[w][lane * 8])[1] = o1;
    __syncthreads();

    const int t = threadIdx.x;
#pragma unroll
    for (int e = 0; e < 2; ++e) {
        const int jk = t * 2 + e;
        spart2[(size_t)bq * 512 + jk] =
            part[0][jk] + part[1][jk] + part[2][jk] + part[3][jk];
    }
}

__global__ __launch_bounds__(512)
void caps_squash0(const float* __restrict__ spart2, float* __restrict__ vsum) {
    const int bl = blockIdx.x;
    const int jk = threadIdx.x;
    float s = 0.f;
#pragma unroll
    for (int p = 0; p < 16; ++p)
        s += spart2[(size_t)(bl * 16 + p) * 512 + jk];
    s *= (1.f / 32.f);
    float q = s * s;
    q += __shfl_xor(q, 1, 64);
    q += __shfl_xor(q, 2, 64);
    q += __shfl_xor(q, 4, 64);
    q += __shfl_xor(q, 8, 64);
    const float scale = q / ((1.f + q) * sqrtf(q + 1e-7f));
    vsum[bl * JK + jk] = scale * s;
}

// ---------------------------------------------------------------------------
// Softmax routing pass: 4096 one-wave blocks = 64 b x 64 chunks (32 i).
// lane: h = lane>>5 (i parity), j = lane&31 -> u_hat[b,i,j,0:16] (32B/lane).
// Round-9 structure (1-step prefetch, e/S divide) EXCEPT the softmax denom:
// DPP row_shr 1/2/4/8 + row_bcast15 adds put sum(lanes 0..31) in lane 31 and
// sum(lanes 32..63) in lane 63; readlane 31/63 + per-half select. VALU-only —
// replaces 5 dependent ds_bpermute ops per iteration.
// ---------------------------------------------------------------------------
__global__ __launch_bounds__(64)
void caps_route1(const unsigned short* __restrict__ uhat,
                 const float* __restrict__ vsum, float* __restrict__ spart) {
    const int lane = threadIdx.x;
    const int bl = blockIdx.x >> 6;
    const int chunk = blockIdx.x & 63;
    const int h = lane >> 5;
    const int j = lane & 31;

    float v[16];
    {
        const float4* vp =
            reinterpret_cast<const float4*>(vsum + bl * JK + j * 16);
        const float4 a0 = vp[0], a1 = vp[1], a2 = vp[2], a3 = vp[3];
        v[0] = a0.x; v[1] = a0.y; v[2] = a0.z; v[3] = a0.w;
        v[4] = a1.x; v[5] = a1.y; v[6] = a1.z; v[7] = a1.w;
        v[8] = a2.x; v[9] = a2.y; v[10] = a2.z; v[11] = a2.w;
        v[12] = a3.x; v[13] = a3.y; v[14] = a3.z; v[15] = a3.w;
    }

    float acc[16];
#pragma unroll
    for (int k = 0; k < 16; ++k) acc[k] = 0.f;

    const unsigned short* up =
        uhat + ((size_t)bl * I_ + chunk * 32 + h) * JK + j * 16;

    uint4 c0 = reinterpret_cast<const uint4*>(up)[0];
    uint4 c1 = reinterpret_cast<const uint4*>(up)[1];

#pragma unroll 4
    for (int t = 0; t < 16; ++t) {
        uint4 n0, n1;
        if (t < 15) {
            const uint4* np =
                reinterpret_cast<const uint4*>(up + (size_t)(t + 1) * 2 * JK);
            n0 = np[0];
            n1 = np[1];
        }
        float u[16];
        unpack8(c0, u);
        unpack8(c1, u + 8);
        float p = 0.f;
#pragma unroll
        for (int k = 0; k < 16; ++k) p += u[k] * v[k];
        const float e = __expf(p);  // |p| bounded; f32-safe
        // --- DPP reduction: per-32-half sum of e, VALU pipe only ---
        float S = e;
        S = dpp_add<0x111>(S);  // row_shr:1
        S = dpp_add<0x112>(S);  // row_shr:2
        S = dpp_add<0x114>(S);  // row_shr:4
        S = dpp_add<0x118>(S);  // row_shr:8  -> lane 15 of each 16-row = rowsum
        S = dpp_add<0x142>(S);  // row_bcast15 -> lane 31/63 = 32-half sums
        union { float f; int i; } sv, lo, hi;
        sv.f = S;
        lo.i = __builtin_amdgcn_readlane(sv.i, 31);
        hi.i = __builtin_amdgcn_readlane(sv.i, 63);
        const float Ssel = (h == 0) ? lo.f : hi.f;
        const float c = e / Ssel;
#pragma unroll
        for (int k = 0; k < 16; ++k) acc[k] += c * u[k];
        c0 = n0;
        c1 = n1;
    }

    // merge the two i-parity halves (same (b,j,k))
#pragma unroll
    for (int k = 0; k < 16; ++k) acc[k] += __shfl_xor(acc[k], 32, 64);

    if (h == 0) {
        float* sp = spart + ((size_t)chunk * B_ + bl) * JK + j * 16;
#pragma unroll
        for (int q = 0; q < 4; ++q) {
            float4 o;
            o.x = acc[q * 4 + 0]; o.y = acc[q * 4 + 1];
            o.z = acc[q * 4 + 2]; o.w = acc[q * 4 + 3];
            reinterpret_cast<float4*>(sp)[q] = o;
        }
    }
}

// ---------------------------------------------------------------------------
// Squash for rounds 1,2: reduce spart[64][B][512].
// MODE 1: vsum += v.  MODE 2: out = v.
// ---------------------------------------------------------------------------
template <int MODE>
__global__ __launch_bounds__(512)
void caps_squash(const float* __restrict__ spart, float* __restrict__ vsum,
                 float* __restrict__ out) {
    const int bl = blockIdx.x;
    const int jk = threadIdx.x;
    float s = 0.f;
#pragma unroll 8
    for (int p = 0; p < 64; ++p)
        s += spart[((size_t)p * B_ + bl) * JK + jk];
    float q = s * s;
    q += __shfl_xor(q, 1, 64);
    q += __shfl_xor(q, 2, 64);
    q += __shfl_xor(q, 4, 64);
    q += __shfl_xor(q, 8, 64);
    const float scale = q / ((1.f + q) * sqrtf(q + 1e-7f));
    const float v = scale * s;
    if (MODE == 1) vsum[bl * JK + jk] += v;
    else           out[(size_t)bl * JK + jk] = v;
}

// ---------------------------------------------------------------------------
extern "C" void kernel_launch(void* const* d_in, const int* in_sizes, int n_in,
                              void* d_out, int out_size, void* d_ws,
                              size_t ws_size, hipStream_t stream) {
    const float* x = (const float*)d_in[0];  // [B,I,D] f32
    const float* W = (const float*)d_in[1];  // [I,J,D,K] f32
    float* out = (float*)d_out;              // [B,J,K] f32

    char* ws = (char*)d_ws;
    unsigned short* uhat = (unsigned short*)ws;                // 128 MiB
    float* spart = (float*)(ws + (size_t)B_ * I_ * JK * 2);    // 8 MiB
    float* vsum = spart + (size_t)64 * B_ * JK;                // 128 KiB

    caps_produce<<<I_, 256, 0, stream>>>(x, W, uhat);

    caps_sum0<<<1024, 256, 0, stream>>>(uhat, spart);
    caps_squash0<<<B_, 512, 0, stream>>>(spart, vsum);

    caps_route1<<<4096, 64, 0, stream>>>(uhat, vsum, spart);
    caps_squash<1><<<B_, 512, 0, stream>>>(spart, vsum, out);

    caps_route1<<<4096, 64, 0, stream>>>(uhat, vsum, spart);
    caps_squash<2><<<B_, 512, 0, stream>>>(spart, vsum, out);
}